// Round 4
// baseline (614.314 us; speedup 1.0000x reference)
//
#include <hip/hip_runtime.h>
#include <hip/hip_fp16.h>

// AffineCouplingBlock MI355X — Round 4: fused both stages, NT=4 (64 pts/wave),
// double-buffered B-fragments, no inline-asm fences (intra-wave DS is in-order;
// compiler alias analysis preserves program order of LDS ops).
// B=64,T=4096,C=64,H=W=64,COND=16,IN=81(->96 pad),HID=128.
// comb col layout (K-permuted in prep): [lf 0..63][cond 64..79][z 80][0 81..95]

#define NPTS (64 * 4096)
#define ZSIZE (NPTS * 2)

typedef _Float16 f16x8 __attribute__((ext_vector_type(8)));
typedef float f32x4 __attribute__((ext_vector_type(4)));

// ws layout (halfs): W0f [4][3][8][{hi,lo}x512] | W1f [12][4][8][1024] | W2h [4][128]
#define W0F_HALFS (4 * 3 * 8 * 1024)   // 98304
#define W1F_HALFS (12 * 4 * 8 * 1024)  // 393216

// ---------------------------------------------------------------------------
// Prep: fragmentize weights into per-lane-coalesced fp16 hi/lo chunks.
// Fragment slot (lane=16g+c, j) holds B[k=kt*32+8g+j][n=n0*16+c] = W[n][k'].
// A-frags use the same slot->k map, so any HW k-order bijection cancels.
// Runs every launch (harness re-poisons ws).
// ---------------------------------------------------------------------------
__global__ void prep_kernel(const float* __restrict__ W0, const float* __restrict__ W1,
                            const float* __restrict__ W2, _Float16* __restrict__ W0f,
                            _Float16* __restrict__ W1f, _Float16* __restrict__ W2h,
                            float* __restrict__ out_ld) {
    const int t0 = blockIdx.x * blockDim.x + threadIdx.x;
    const int stride = gridDim.x * blockDim.x;
    if (t0 < 64) out_ld[t0] = 0.f;
    // W0: [4][128][81] -> padded K=96, col permutation (new k 0..79 <- old k+1, 80 <- old 0)
    for (int t = t0; t < 4 * 3 * 8 * 64 * 8; t += stride) {
        int j = t & 7, r = t >> 3;
        int l = r & 63; r >>= 6;
        int n0 = r & 7; r >>= 3;
        int kt = r % 3, idx = r / 3;
        int k = kt * 32 + (l >> 4) * 8 + j;
        int n = n0 * 16 + (l & 15);
        float v = 0.f;
        if (k <= 80) {
            int ko = (k < 80) ? (k + 1) : 0;
            v = W0[(idx * 128 + n) * 81 + ko];
        }
        _Float16 hi = (_Float16)v;
        _Float16 lo = (_Float16)(v - (float)hi);
        int base = ((idx * 3 + kt) * 8 + n0) * 1024;
        W0f[base + l * 8 + j] = hi;
        W0f[base + 512 + l * 8 + j] = lo;
    }
    // W1: [12][128][128]
    for (int t = t0; t < 12 * 4 * 8 * 64 * 8; t += stride) {
        int j = t & 7, r = t >> 3;
        int l = r & 63; r >>= 6;
        int n0 = r & 7; r >>= 3;
        int kt = r & 3, m = r >> 2;
        int k = kt * 32 + (l >> 4) * 8 + j;
        int n = n0 * 16 + (l & 15);
        float v = W1[(m * 128 + n) * 128 + k];
        _Float16 hi = (_Float16)v;
        _Float16 lo = (_Float16)(v - (float)hi);
        int base = ((m * 4 + kt) * 8 + n0) * 1024;
        W1f[base + l * 8 + j] = hi;
        W1f[base + 512 + l * 8 + j] = lo;
    }
    for (int t = t0; t < 512; t += stride) W2h[t] = (_Float16)W2[t];
}

// ---------------------------------------------------------------------------
// MLP building blocks. A-frags packed flat: A[t2*KT+kt], t2 = 16-row tile 0..3.
// ---------------------------------------------------------------------------
template <int KT>
__device__ __forceinline__ void load_bfrag(f16x8* B, const _Float16* __restrict__ wfb,
                                           int n0, int lane) {
#pragma unroll
    for (int kt = 0; kt < KT; ++kt) {
        const _Float16* c2 = wfb + kt * 8192 + n0 * 1024 + lane * 8;
        B[2 * kt] = *(const f16x8*)c2;           // hi
        B[2 * kt + 1] = *(const f16x8*)(c2 + 512);  // lo
    }
}

template <int KT>
__device__ __forceinline__ void compute_n0(const f16x8* A, const f16x8* B,
                                           const float* __restrict__ bias, int n0,
                                           _Float16 (*hrow)[136], int fr, int fg) {
    const float bb = bias[n0 * 16 + fr];
    f32x4 acc[4];
#pragma unroll
    for (int t2 = 0; t2 < 4; ++t2) acc[t2] = (f32x4){bb, bb, bb, bb};
#pragma unroll
    for (int kt = 0; kt < KT; ++kt) {
#pragma unroll
        for (int t2 = 0; t2 < 4; ++t2)
            acc[t2] = __builtin_amdgcn_mfma_f32_16x16x32_f16(A[t2 * KT + kt], B[2 * kt], acc[t2], 0, 0, 0);
#pragma unroll
        for (int t2 = 0; t2 < 4; ++t2)
            acc[t2] = __builtin_amdgcn_mfma_f32_16x16x32_f16(A[t2 * KT + kt], B[2 * kt + 1], acc[t2], 0, 0, 0);
    }
#pragma unroll
    for (int t2 = 0; t2 < 4; ++t2)
#pragma unroll
        for (int rg = 0; rg < 4; ++rg) {
            const float v = acc[t2][rg];
            const float sv = v * __builtin_amdgcn_rcpf(1.f + __expf(-v));
            hrow[t2 * 16 + fg * 4 + rg][n0 * 16 + fr] = (_Float16)sv;
        }
}

template <int KT>
__device__ __forceinline__ void run_layer(const f16x8* A, const _Float16* __restrict__ wfb,
                                          const float* __restrict__ bias,
                                          _Float16 (*hrow)[136], int lane, int fr, int fg) {
    f16x8 Ba[2 * KT], Bb[2 * KT];
    load_bfrag<KT>(Ba, wfb, 0, lane);
#pragma unroll
    for (int n0 = 0; n0 < 8; n0 += 2) {
        load_bfrag<KT>(Bb, wfb, n0 + 1, lane);
        compute_n0<KT>(A, Ba, bias, n0, hrow, fr, fg);
        if (n0 + 2 < 8) load_bfrag<KT>(Ba, wfb, n0 + 2, lane);
        compute_n0<KT>(A, Bb, bias, n0 + 1, hrow, fr, fg);
    }
}

// ---------------------------------------------------------------------------
// Fused kernel: both coupling stages. 2 waves/block, 64 points/wave (NT=4).
// Per wave LDS rows 0..63 = its points; lane = (hh:1)(pl:5); channels split by hh.
// ---------------------------------------------------------------------------
__global__ __launch_bounds__(128, 2) void fused_kernel(
    const float* __restrict__ x, const float* __restrict__ w, const float* __restrict__ cond,
    const _Float16* __restrict__ W0f, const float* __restrict__ b0,
    const _Float16* __restrict__ W1f, const float* __restrict__ b1,
    const _Float16* __restrict__ W2h, const float* __restrict__ b2,
    float* __restrict__ out) {
    __shared__ __align__(16) _Float16 hlds[2][64][136];
    __shared__ __align__(8) _Float16 w2l[4][128];

    const int tid = threadIdx.x;
    ((unsigned int*)w2l)[tid] = ((const unsigned int*)W2h)[tid];
    ((unsigned int*)w2l)[tid + 128] = ((const unsigned int*)W2h)[tid + 128];
    __syncthreads();  // only block-wide barrier (w2l is cross-wave)

    const int o = blockIdx.x;
    const int wg = (o & 7) * 256 + (o >> 3);  // XCD-bijective swizzle (2048 = 8*256)
    const int wv = tid >> 6, lane = tid & 63;
    const int pl = lane & 31;  // local point within 32-half
    const int hh = lane >> 5;  // channel/K half
    const int fr = lane & 15, fg = lane >> 4;
    const int pbase = wg * 128 + wv * 64;
    const int b = wg >> 5;  // batch (block spans 128 consecutive points)

    float xa[2], xb[2], za[2], zb[2];
#pragma unroll
    for (int q = 0; q < 2; ++q) {
        const float2 xv = *(const float2*)&x[2 * (pbase + 32 * q + pl)];
        xa[q] = xv.x;
        xb[q] = xv.y;
    }

    __half2 cpk[8];
    {
        const float* cb = cond + b * 16;
#pragma unroll
        for (int j = 0; j < 8; ++j) cpk[j] = __floats2half2_rn(cb[2 * j], cb[2 * j + 1]);
    }

    float s_acc = 0.f;

    for (int stage = 0; stage < 2; ++stage) {
        // ---- gather both point-halves into comb rows ----
#pragma unroll
        for (int q = 0; q < 2; ++q) {
            const float cx = (stage == 0) ? xa[q] : za[q];  // grid x = cur_z[...,0]
            const float cy = xb[q];                         // grid y = z_b (unchanged)
            const float gx = cx * 2.f - 1.f, gy = cy * 2.f - 1.f;
            const float ixf = (gx + 1.f) * 0.5f * 63.f;
            const float iyf = (gy + 1.f) * 0.5f * 63.f;
            const float ix0f = floorf(ixf), iy0f = floorf(iyf);
            const float ix1f = ix0f + 1.f, iy1f = iy0f + 1.f;
            const float wx1 = ixf - ix0f, wx0 = 1.f - wx1;
            const float wy1 = iyf - iy0f, wy0 = 1.f - wy1;
            const bool vx0 = (ix0f >= 0.f) && (ix0f <= 63.f);
            const bool vx1 = (ix1f >= 0.f) && (ix1f <= 63.f);
            const bool vy0 = (iy0f >= 0.f) && (iy0f <= 63.f);
            const bool vy1 = (iy1f >= 0.f) && (iy1f <= 63.f);
            const float f00 = (vy0 && vx0) ? wy0 * wx0 : 0.f;
            const float f01 = (vy0 && vx1) ? wy0 * wx1 : 0.f;
            const float f10 = (vy1 && vx0) ? wy1 * wx0 : 0.f;
            const float f11 = (vy1 && vx1) ? wy1 * wx1 : 0.f;
            const int xi0 = (int)fminf(fmaxf(ix0f, 0.f), 63.f);
            const int xi1 = (int)fminf(fmaxf(ix1f, 0.f), 63.f);
            const int yi0 = (int)fminf(fmaxf(iy0f, 0.f), 63.f);
            const int yi1 = (int)fminf(fmaxf(iy1f, 0.f), 63.f);
            const int o00 = yi0 * 64 + xi0, o01 = yi0 * 64 + xi1;
            const int o10 = yi1 * 64 + xi0, o11 = yi1 * 64 + xi1;

            const int row = 32 * q + pl;
            const float* wq = w + ((size_t)b << 18) + ((size_t)hh << 17);
#pragma unroll 4
            for (int jj = 0; jj < 16; ++jj) {
                const float* wcA = wq + ((2 * jj) << 12);
                const float* wcB = wcA + 4096;
                const float lfA = f00 * wcA[o00] + f01 * wcA[o01] + f10 * wcA[o10] + f11 * wcA[o11];
                const float lfB = f00 * wcB[o00] + f01 * wcB[o01] + f10 * wcB[o10] + f11 * wcB[o11];
                *(__half2*)&hlds[wv][row][hh * 32 + 2 * jj] = __floats2half2_rn(lfA, lfB);
            }
            if (hh == 0) {
                const float zk = (stage == 0) ? xb[q] : za[q];  // z_keep
#pragma unroll
                for (int j2 = 0; j2 < 8; ++j2) *(__half2*)&hlds[wv][row][64 + 2 * j2] = cpk[j2];
                *(__half2*)&hlds[wv][row][80] = __floats2half2_rn(zk, 0.f);
#pragma unroll
                for (int j2 = 41; j2 < 48; ++j2)
                    *(__half2*)&hlds[wv][row][2 * j2] = __floats2half2_rn(0.f, 0.f);
            }
        }

        // comb A-frags held in regs (layer 0 of BOTH chains; h overwrites comb)
        f16x8 cfr[12];
#pragma unroll
        for (int t2 = 0; t2 < 4; ++t2)
#pragma unroll
            for (int kt = 0; kt < 3; ++kt)
                cfr[t2 * 3 + kt] = *(const f16x8*)&hlds[wv][t2 * 16 + fr][kt * 32 + fg * 8];

        float yv[2][2];
        for (int chain = 0; chain < 2; ++chain) {
            const int idx = stage * 2 + chain;
            run_layer<3>(cfr, W0f + idx * 3 * 8192, b0 + idx * 128, hlds[wv], lane, fr, fg);
            for (int l = 0; l < 3; ++l) {
                f16x8 afr[16];
#pragma unroll
                for (int t2 = 0; t2 < 4; ++t2)
#pragma unroll
                    for (int kt = 0; kt < 4; ++kt)
                        afr[t2 * 4 + kt] = *(const f16x8*)&hlds[wv][t2 * 16 + fr][kt * 32 + fg * 8];
                run_layer<4>(afr, W1f + (idx * 3 + l) * 4 * 8192, b1 + (idx * 3 + l) * 128,
                             hlds[wv], lane, fr, fg);
            }
            // final dot: y = h3 . w2 + b2 ; lanes split K by hh, points by halves
            const _Float16* w2row = &w2l[idx][0];
#pragma unroll
            for (int h2 = 0; h2 < 2; ++h2) {
                const _Float16* hrow2 = &hlds[wv][32 * h2 + pl][0];
                const int kb = hh * 64;
                float part = 0.f;
#pragma unroll 8
                for (int j = 0; j < 32; ++j) {
                    const float2 hf = __half22float2(*(const __half2*)&hrow2[kb + 2 * j]);
                    const float2 wf = __half22float2(*(const __half2*)&w2row[kb + 2 * j]);
                    part = fmaf(hf.x, wf.x, part);
                    part = fmaf(hf.y, wf.y, part);
                }
                part += __shfl_xor(part, 32);
                yv[chain][h2] = part + b2[idx];
            }
        }

        // ---- z update + log_det accumulate ----
#pragma unroll
        for (int q = 0; q < 2; ++q) {
            const float ys = yv[0][q];
            // tanh(y) = 1 - 2/(exp(2y)+1)  (branchless, handles +-inf limits)
            const float s = 1.5f * (1.f - 2.f * __builtin_amdgcn_rcpf(__expf(2.f * ys) + 1.f));
            const float t = yv[1][q];
            if (stage == 0)
                za[q] = fmaf(xa[q], __expf(s), t);
            else
                zb[q] = fmaf(xb[q], __expf(s), t);
            s_acc += (hh == 0) ? s : 0.f;
        }
    }

    if (hh == 0) {
        *(float2*)&out[2 * (pbase + pl)] = make_float2(za[0], zb[0]);
        *(float2*)&out[2 * (pbase + 32 + pl)] = make_float2(za[1], zb[1]);
    }
    float r = s_acc;
#pragma unroll
    for (int off = 1; off <= 32; off <<= 1) r += __shfl_xor(r, off);
    if (lane == 0) atomicAdd(out + ZSIZE + b, r);
}

// ---------------------------------------------------------------------------
extern "C" void kernel_launch(void* const* d_in, const int* in_sizes, int n_in,
                              void* d_out, int out_size, void* d_ws, size_t ws_size,
                              hipStream_t stream) {
    const float* x = (const float*)d_in[0];
    const float* w = (const float*)d_in[1];
    const float* cond = (const float*)d_in[2];
    const float* W0 = (const float*)d_in[3];
    const float* b0 = (const float*)d_in[4];
    const float* W1 = (const float*)d_in[5];
    const float* b1 = (const float*)d_in[6];
    const float* W2 = (const float*)d_in[7];
    const float* b2 = (const float*)d_in[8];
    float* out = (float*)d_out;

    _Float16* W0f = (_Float16*)d_ws;
    _Float16* W1f = W0f + W0F_HALFS;
    _Float16* W2h = W1f + W1F_HALFS;  // total ~0.94 MB

    prep_kernel<<<256, 256, 0, stream>>>(W0, W1, W2, W0f, W1f, W2h, out + ZSIZE);
    fused_kernel<<<2048, 128, 0, stream>>>(x, w, cond, W0f, b0, W1f, b1, W2h, b2, out);
}